// Round 5
// baseline (1779.992 us; speedup 1.0000x reference)
//
#include <hip/hip_runtime.h>
#include <math.h>

// ---------------------------------------------------------------------------
// GCN 3-layer forward for MI355X.
// Pipeline:
//   deg init -> atomic deg accum -> rsqrt -> per-edge norm (once)
//   per layer: GEMM (W^T in LDS, fused self-loop+bias epilogue, fused ReLU on
//   input load) -> per-edge atomic scatter-aggregate
//   final: in-place log_softmax on d_out
// ---------------------------------------------------------------------------

__global__ void k_init_deg(float* __restrict__ deg, int n) {
    int i = blockIdx.x * blockDim.x + threadIdx.x;
    if (i < n) deg[i] = 1.0f;   // self-loop weight
}

__global__ void k_deg_accum(const int* __restrict__ dst, const float* __restrict__ ew,
                            float* __restrict__ deg, int E) {
    int e = blockIdx.x * blockDim.x + threadIdx.x;
    if (e < E) atomicAdd(&deg[dst[e]], ew[e]);
}

__global__ void k_rsqrt(float* __restrict__ deg, int n) {
    int i = blockIdx.x * blockDim.x + threadIdx.x;
    if (i < n) {
        float d = deg[i];
        deg[i] = (d > 0.f) ? rsqrtf(d) : 0.f;
    }
}

__global__ void k_norm(const int* __restrict__ src, const int* __restrict__ dst,
                       const float* __restrict__ ew, const float* __restrict__ dis,
                       float* __restrict__ nrm, int E) {
    int e = blockIdx.x * blockDim.x + threadIdx.x;
    if (e < E) nrm[e] = dis[src[e]] * ew[e] * dis[dst[e]];
}

// GEMM: H = act(X) @ W, one row per wave, lane = output column.
// Epilogue also writes Agg = acc*dis[row]^2 + bias[lane]  (self-loop + bias).
// W^T staged in LDS padded to K+1 -> conflict-free b32 reads
// (bank(lane*(K+1)+k) = (lane+k)%32).
// NOTE: Hout/Agg are NOT __restrict__ — layer 1 legally aliases Agg with X
// (row-local read-before-write, enforced by dataflow).
template<int K, int NOUT, bool RELU_IN>
__global__ void k_gemm(const float* __restrict__ X, const float* __restrict__ W,
                       const float* __restrict__ bias, const float* __restrict__ dis,
                       float* Hout, float* Agg, int nrows) {
    __shared__ float WT[NOUT][K + 1];
    for (int idx = threadIdx.x; idx < K * NOUT; idx += blockDim.x)
        WT[idx % NOUT][idx / NOUT] = W[idx];   // WT[n][k] = W[k][n]
    __syncthreads();

    const int lane = threadIdx.x & 63;
    const int wid  = threadIdx.x >> 6;

    for (int row = blockIdx.x * 4 + wid; row < nrows; row += (int)gridDim.x * 4) {
        const float4* xr = (const float4*)(X + (size_t)row * K);
        float acc = 0.f;
#pragma unroll 4
        for (int k4 = 0; k4 < K / 4; ++k4) {
            float4 xv = xr[k4];            // same addr across wave -> broadcast
            if (RELU_IN) {
                xv.x = fmaxf(xv.x, 0.f); xv.y = fmaxf(xv.y, 0.f);
                xv.z = fmaxf(xv.z, 0.f); xv.w = fmaxf(xv.w, 0.f);
            }
            int k = k4 * 4;
            if (lane < NOUT)
                acc += xv.x * WT[lane][k]     + xv.y * WT[lane][k + 1]
                     + xv.z * WT[lane][k + 2] + xv.w * WT[lane][k + 3];
        }
        if (lane < NOUT) {
            float d = dis[row];
            Hout[(size_t)row * NOUT + lane] = acc;
            Agg[(size_t)row * NOUT + lane]  = acc * d * d + bias[lane];
        }
    }
}

// One wave per edge; lane j handles feature j. agg[dst] += h[src] * norm.
template<int F>
__global__ void k_edge_agg(const float* __restrict__ h, const float* __restrict__ nrm,
                           const int* __restrict__ src, const int* __restrict__ dst,
                           float* agg, int E) {
    const int lane = threadIdx.x & 63;
    int gw = (int)((blockIdx.x * blockDim.x + threadIdx.x) >> 6);
    int nw = (int)((gridDim.x * blockDim.x) >> 6);
    for (int e = gw; e < E; e += nw) {
        int s = src[e], d = dst[e];
        float w = nrm[e];
        if (lane < F)
            atomicAdd(&agg[(size_t)d * F + lane], h[(size_t)s * F + lane] * w);
    }
}

// In-place log_softmax over C columns; one wave per row.
template<int C>
__global__ void k_logsoftmax(float* __restrict__ io, int n) {
    const int lane = threadIdx.x & 63;
    int row = (int)((blockIdx.x * blockDim.x + threadIdx.x) >> 6);
    if (row >= n) return;
    float v = (lane < C) ? io[(size_t)row * C + lane] : -INFINITY;
    float m = v;
#pragma unroll
    for (int off = 32; off; off >>= 1) m = fmaxf(m, __shfl_xor(m, off));
    float e = (lane < C) ? expf(v - m) : 0.f;
    float s = e;
#pragma unroll
    for (int off = 32; off; off >>= 1) s += __shfl_xor(s, off);
    float ls = logf(s);
    if (lane < C) io[(size_t)row * C + lane] = v - m - ls;
}

extern "C" void kernel_launch(void* const* d_in, const int* in_sizes, int n_in,
                              void* d_out, int out_size, void* d_ws, size_t ws_size,
                              hipStream_t stream) {
    const float* x  = (const float*)d_in[0];
    const int*   ei = (const int*)  d_in[1];
    const float* ew = (const float*)d_in[2];
    const float* W0 = (const float*)d_in[3];
    const float* b0 = (const float*)d_in[4];
    const float* W1 = (const float*)d_in[5];
    const float* b1 = (const float*)d_in[6];
    const float* W2 = (const float*)d_in[7];
    const float* b2 = (const float*)d_in[8];

    const int E   = in_sizes[2];            // 1600000
    const int H   = in_sizes[4];            // 64
    const int Fin = in_sizes[3] / H;        // 256
    const int N   = in_sizes[0] / Fin;      // 100000
    (void)n_in; (void)out_size; (void)ws_size;

    const int* srcv = ei;                   // edge_index[0]
    const int* dstv = ei + E;               // edge_index[1]

    float* ws   = (float*)d_ws;
    float* dis  = ws;                                   // N
    float* nrm  = dis + (((size_t)N + 63) & ~(size_t)63);   // E
    float* bufA = nrm + (((size_t)E + 63) & ~(size_t)63);   // N*64 (h)
    float* bufB = bufA + (size_t)N * 64;                    // N*64 (agg)
    float* outf = (float*)d_out;                            // N*40

    const int TB = 256;

    // ---- norm precompute (shared across layers) ----
    k_init_deg <<<(N + TB - 1) / TB, TB, 0, stream>>>(dis, N);
    k_deg_accum<<<(E + TB - 1) / TB, TB, 0, stream>>>(dstv, ew, dis, E);
    k_rsqrt    <<<(N + TB - 1) / TB, TB, 0, stream>>>(dis, N);
    k_norm     <<<(E + TB - 1) / TB, TB, 0, stream>>>(srcv, dstv, ew, dis, nrm, E);

    const int gemmGrid = (N + 3) / 4;
    const int aggGrid  = 8192;

    // ---- layer 0: x(256) -> 64, relu handled on next layer's load ----
    k_gemm<256, 64, false><<<gemmGrid, TB, 0, stream>>>(x, W0, b0, dis, bufA, bufB, N);
    k_edge_agg<64><<<aggGrid, TB, 0, stream>>>(bufA, nrm, srcv, dstv, bufB, E);

    // ---- layer 1: 64 -> 64 (input = relu(bufB)); Agg aliases X row-locally ----
    k_gemm<64, 64, true><<<gemmGrid, TB, 0, stream>>>(bufB, W1, b1, dis, bufA, bufB, N);
    k_edge_agg<64><<<aggGrid, TB, 0, stream>>>(bufA, nrm, srcv, dstv, bufB, E);

    // ---- layer 2: 64 -> 40, agg directly in d_out ----
    k_gemm<64, 40, true><<<gemmGrid, TB, 0, stream>>>(bufB, W2, b2, dis, bufA, outf, N);
    k_edge_agg<40><<<aggGrid, TB, 0, stream>>>(bufA, nrm, srcv, dstv, outf, E);

    // ---- log_softmax in-place on d_out ----
    k_logsoftmax<40><<<gemmGrid, TB, 0, stream>>>(outf, N);
}

// Round 6
// 1161.293 us; speedup vs baseline: 1.5328x; 1.5328x over previous
//
#include <hip/hip_runtime.h>
#include <math.h>

// ---------------------------------------------------------------------------
// GCN 3-layer forward for MI355X.
//   deg init -> atomic deg accum -> rsqrt -> per-edge norm (once)
//   per layer: tiled GEMM (BM64xBN64xBK32, 4x4 reg tile, fused self-loop+bias
//   epilogue, fused ReLU on input load) -> per-edge atomic scatter-aggregate
//   final: in-place log_softmax on d_out
// R5: replaced row-per-wave GEMM (733us, VALUBusy 20%, occ 23% LDS-capped,
//     wave-uniform 16B loads) with tiled GEMM. Roofline ~25-40us.
// ---------------------------------------------------------------------------

__global__ void k_init_deg(float* __restrict__ deg, int n) {
    int i = blockIdx.x * blockDim.x + threadIdx.x;
    if (i < n) deg[i] = 1.0f;   // self-loop weight
}

__global__ void k_deg_accum(const int* __restrict__ dst, const float* __restrict__ ew,
                            float* __restrict__ deg, int E) {
    int e = blockIdx.x * blockDim.x + threadIdx.x;
    if (e < E) atomicAdd(&deg[dst[e]], ew[e]);
}

__global__ void k_rsqrt(float* __restrict__ deg, int n) {
    int i = blockIdx.x * blockDim.x + threadIdx.x;
    if (i < n) {
        float d = deg[i];
        deg[i] = (d > 0.f) ? rsqrtf(d) : 0.f;
    }
}

__global__ void k_norm(const int* __restrict__ src, const int* __restrict__ dst,
                       const float* __restrict__ ew, const float* __restrict__ dis,
                       float* __restrict__ nrm, int E) {
    int e = blockIdx.x * blockDim.x + threadIdx.x;
    if (e < E) nrm[e] = dis[src[e]] * ew[e] * dis[dst[e]];
}

// Tiled GEMM: H = act(X) @ W  (M=nrows, K, N=NOUT<=64).
// Block: 256 threads -> 64 rows x 64 cols, each thread 4x4 outputs.
// As staged TRANSPOSED [k][m] (pad 68: 16B-aligned b128 reads, ~4-way store
// conflict is negligible vs 1024 compute cyc/tile). Bs [k][n] pad 68.
// Epilogue: Hout = acc; Agg = acc*dis[row]^2 + bias  (self-loop + bias).
// Layer-1 aliasing (Agg==X buffer) is safe: block reads only its own 64 rows
// (all reads precede last barrier), writes those rows only in epilogue;
// blocks are row-disjoint. Hout/Agg deliberately NOT __restrict__.
template<int K, int NOUT, bool RELU_IN>
__global__ __launch_bounds__(256) void k_gemm(
    const float* __restrict__ X, const float* __restrict__ W,
    const float* __restrict__ bias, const float* __restrict__ dis,
    float* Hout, float* Agg, int nrows)
{
    constexpr int BM = 64, BN = 64, BK = 32;
    __shared__ float As[BK][BM + 4];   // As[k][m], row stride 68
    __shared__ float Bs[BK][BN + 4];

    const int tid = (int)threadIdx.x;
    const int tx  = tid & 15;          // col group: cols tx*4..+3
    const int ty  = tid >> 4;          // row group: rows ty*4..+3
    const int r0  = (int)blockIdx.x * BM;

    float acc[4][4] = {};

    for (int k0 = 0; k0 < K; k0 += BK) {
        // stage As: 64 rows x 32 k, coalesced (lane = consecutive k)
#pragma unroll
        for (int i = 0; i < (BM * BK) / 256; ++i) {
            int e  = tid + i * 256;
            int r  = e >> 5;           // /32
            int kk = e & 31;
            int row = r0 + r;
            float v = (row < nrows) ? X[(size_t)row * K + (k0 + kk)] : 0.f;
            if (RELU_IN) v = fmaxf(v, 0.f);
            As[kk][r] = v;
        }
        // stage Bs: 32 k x 64 cols (zero-pad cols >= NOUT)
#pragma unroll
        for (int i = 0; i < (BK * BN) / 256; ++i) {
            int e  = tid + i * 256;
            int kk = e >> 6;           // /64
            int c  = e & 63;
            Bs[kk][c] = (c < NOUT) ? W[(size_t)(k0 + kk) * NOUT + c] : 0.f;
        }
        __syncthreads();
#pragma unroll
        for (int kk = 0; kk < BK; ++kk) {
            float4 a = *(const float4*)&As[kk][ty * 4];
            float4 b = *(const float4*)&Bs[kk][tx * 4];
            acc[0][0] += a.x * b.x; acc[0][1] += a.x * b.y; acc[0][2] += a.x * b.z; acc[0][3] += a.x * b.w;
            acc[1][0] += a.y * b.x; acc[1][1] += a.y * b.y; acc[1][2] += a.y * b.z; acc[1][3] += a.y * b.w;
            acc[2][0] += a.z * b.x; acc[2][1] += a.z * b.y; acc[2][2] += a.z * b.z; acc[2][3] += a.z * b.w;
            acc[3][0] += a.w * b.x; acc[3][1] += a.w * b.y; acc[3][2] += a.w * b.z; acc[3][3] += a.w * b.w;
        }
        __syncthreads();
    }

    // epilogue (NOUT % 4 == 0 for all instances: 64/64/40)
    if (tx * 4 + 3 < NOUT) {
        float4 bv = *(const float4*)&bias[tx * 4];
#pragma unroll
        for (int i = 0; i < 4; ++i) {
            int row = r0 + ty * 4 + i;
            if (row < nrows) {
                float d  = dis[row];
                float dd = d * d;
                float4 h = make_float4(acc[i][0], acc[i][1], acc[i][2], acc[i][3]);
                *(float4*)&Hout[(size_t)row * NOUT + tx * 4] = h;
                float4 g = make_float4(h.x * dd + bv.x, h.y * dd + bv.y,
                                       h.z * dd + bv.z, h.w * dd + bv.w);
                *(float4*)&Agg[(size_t)row * NOUT + tx * 4] = g;
            }
        }
    }
}

// One wave per edge; lane j handles feature j. agg[dst] += h[src] * norm.
template<int F>
__global__ void k_edge_agg(const float* __restrict__ h, const float* __restrict__ nrm,
                           const int* __restrict__ src, const int* __restrict__ dst,
                           float* agg, int E) {
    const int lane = threadIdx.x & 63;
    int gw = (int)((blockIdx.x * blockDim.x + threadIdx.x) >> 6);
    int nw = (int)((gridDim.x * blockDim.x) >> 6);
    for (int e = gw; e < E; e += nw) {
        int s = src[e], d = dst[e];
        float w = nrm[e];
        if (lane < F)
            atomicAdd(&agg[(size_t)d * F + lane], h[(size_t)s * F + lane] * w);
    }
}

// In-place log_softmax over C columns; one wave per row.
template<int C>
__global__ void k_logsoftmax(float* __restrict__ io, int n) {
    const int lane = threadIdx.x & 63;
    int row = (int)((blockIdx.x * blockDim.x + threadIdx.x) >> 6);
    if (row >= n) return;
    float v = (lane < C) ? io[(size_t)row * C + lane] : -INFINITY;
    float m = v;
#pragma unroll
    for (int off = 32; off; off >>= 1) m = fmaxf(m, __shfl_xor(m, off));
    float e = (lane < C) ? expf(v - m) : 0.f;
    float s = e;
#pragma unroll
    for (int off = 32; off; off >>= 1) s += __shfl_xor(s, off);
    float ls = logf(s);
    if (lane < C) io[(size_t)row * C + lane] = v - m - ls;
}

extern "C" void kernel_launch(void* const* d_in, const int* in_sizes, int n_in,
                              void* d_out, int out_size, void* d_ws, size_t ws_size,
                              hipStream_t stream) {
    const float* x  = (const float*)d_in[0];
    const int*   ei = (const int*)  d_in[1];
    const float* ew = (const float*)d_in[2];
    const float* W0 = (const float*)d_in[3];
    const float* b0 = (const float*)d_in[4];
    const float* W1 = (const float*)d_in[5];
    const float* b1 = (const float*)d_in[6];
    const float* W2 = (const float*)d_in[7];
    const float* b2 = (const float*)d_in[8];

    const int E   = in_sizes[2];            // 1600000
    const int H   = in_sizes[4];            // 64
    const int Fin = in_sizes[3] / H;        // 256
    const int N   = in_sizes[0] / Fin;      // 100000
    (void)n_in; (void)out_size; (void)ws_size;

    const int* srcv = ei;                   // edge_index[0]
    const int* dstv = ei + E;               // edge_index[1]

    float* ws   = (float*)d_ws;
    float* dis  = ws;                                   // N
    float* nrm  = dis + (((size_t)N + 63) & ~(size_t)63);   // E
    float* bufA = nrm + (((size_t)E + 63) & ~(size_t)63);   // N*64 (h)
    float* bufB = bufA + (size_t)N * 64;                    // N*64 (agg)
    float* outf = (float*)d_out;                            // N*40

    const int TB = 256;

    // ---- norm precompute (shared across layers) ----
    k_init_deg <<<(N + TB - 1) / TB, TB, 0, stream>>>(dis, N);
    k_deg_accum<<<(E + TB - 1) / TB, TB, 0, stream>>>(dstv, ew, dis, E);
    k_rsqrt    <<<(N + TB - 1) / TB, TB, 0, stream>>>(dis, N);
    k_norm     <<<(E + TB - 1) / TB, TB, 0, stream>>>(srcv, dstv, ew, dis, nrm, E);

    const int gemmGrid = (N + 63) / 64;     // 1563 row-tiles
    const int aggGrid  = 8192;

    // ---- layer 0: x(256) -> 64, relu handled on next layer's load ----
    k_gemm<256, 64, false><<<gemmGrid, TB, 0, stream>>>(x, W0, b0, dis, bufA, bufB, N);
    k_edge_agg<64><<<aggGrid, TB, 0, stream>>>(bufA, nrm, srcv, dstv, bufB, E);

    // ---- layer 1: 64 -> 64 (input = relu(bufB)); Agg aliases X row-locally ----
    k_gemm<64, 64, true><<<gemmGrid, TB, 0, stream>>>(bufB, W1, b1, dis, bufA, bufB, N);
    k_edge_agg<64><<<aggGrid, TB, 0, stream>>>(bufA, nrm, srcv, dstv, bufB, E);

    // ---- layer 2: 64 -> 40, agg directly in d_out ----
    k_gemm<64, 40, true><<<gemmGrid, TB, 0, stream>>>(bufB, W2, b2, dis, bufA, outf, N);
    k_edge_agg<40><<<aggGrid, TB, 0, stream>>>(bufA, nrm, srcv, dstv, outf, E);

    // ---- log_softmax in-place on d_out ----
    k_logsoftmax<40><<<(N * 64 + TB - 1) / TB, TB, 0, stream>>>(outf, N);
}

// Round 7
// 586.146 us; speedup vs baseline: 3.0368x; 1.9812x over previous
//
#include <hip/hip_runtime.h>
#include <math.h>

// ---------------------------------------------------------------------------
// GCN 3-layer forward for MI355X.
// R5: tiled GEMM (733us/GEMM -> fixed; total 1780->1161us).
// R6 profile: 3x k_edge_agg @337us dominate; WRITE_SIZE=400MB/dispatch =
//   exactly E*64lanes*4B -> every atomicAdd is a memory-side write. Atomic-
//   traffic-bound. Fix: device-built CSR (dst-grouped), gather-based
//   aggregation with ZERO atomics in the per-layer path.
// Pipeline:
//   init -> deg/cnt histogram -> rsqrt -> 3-kernel exclusive scan -> scatter
//   (builds srcP/nrmP, fuses norm) ;
//   per layer: tiled GEMM (Hout only) -> k_node_agg (self-loop+bias fused,
//   serial neighbor gather, no atomics) ; final log_softmax.
// ---------------------------------------------------------------------------

__global__ void k_init(float* __restrict__ deg, int* __restrict__ cnt, int n) {
    int i = blockIdx.x * blockDim.x + threadIdx.x;
    if (i < n) { deg[i] = 1.0f; cnt[i] = 0; }   // self-loop weight 1
}

__global__ void k_deg_cnt(const int* __restrict__ dst, const float* __restrict__ ew,
                          float* __restrict__ deg, int* __restrict__ cnt, int E) {
    int e = blockIdx.x * blockDim.x + threadIdx.x;
    if (e < E) {
        int d = dst[e];
        atomicAdd(&deg[d], ew[e]);
        atomicAdd(&cnt[d], 1);
    }
}

__global__ void k_rsqrt(float* __restrict__ deg, int n) {
    int i = blockIdx.x * blockDim.x + threadIdx.x;
    if (i < n) {
        float d = deg[i];
        deg[i] = (d > 0.f) ? rsqrtf(d) : 0.f;
    }
}

// ---- exclusive scan over cnt[N] -> rowptr[N+1], 3 kernels ----
__global__ void k_scan1(const int* __restrict__ cnt, int* __restrict__ excl,
                        int* __restrict__ bsum, int n) {
    __shared__ int sm[256];
    int tid = threadIdx.x;
    int i = blockIdx.x * 256 + tid;
    int v = (i < n) ? cnt[i] : 0;
    sm[tid] = v;
    __syncthreads();
    for (int off = 1; off < 256; off <<= 1) {
        int t = (tid >= off) ? sm[tid - off] : 0;
        __syncthreads();
        sm[tid] += t;
        __syncthreads();
    }
    if (i < n) excl[i] = sm[tid] - v;
    if (tid == 255) bsum[blockIdx.x] = sm[255];
}

__global__ void k_scan2(const int* __restrict__ bsum, int* __restrict__ boff, int nb) {
    __shared__ int sm[512];
    int tid = threadIdx.x;
    int v = (tid < nb) ? bsum[tid] : 0;
    sm[tid] = v;
    __syncthreads();
    for (int off = 1; off < 512; off <<= 1) {
        int t = (tid >= off) ? sm[tid - off] : 0;
        __syncthreads();
        sm[tid] += t;
        __syncthreads();
    }
    boff[tid] = sm[tid] - v;   // exclusive
}

__global__ void k_scan3(int* __restrict__ rowptr, const int* __restrict__ boff,
                        int* __restrict__ cursor, int n, int E) {
    int i = blockIdx.x * blockDim.x + threadIdx.x;
    if (i < n) {
        int r = rowptr[i] + boff[i >> 8];
        rowptr[i] = r;
        cursor[i] = r;
    }
    if (i == 0) rowptr[n] = E;
}

// Scatter edges into dst-grouped slots; fuse norm = dis[s]*ew*dis[d].
__global__ void k_scatter(const int* __restrict__ src, const int* __restrict__ dst,
                          const float* __restrict__ ew, const float* __restrict__ dis,
                          int* __restrict__ cursor, int* __restrict__ srcP,
                          float* __restrict__ nrmP, int E) {
    int e = blockIdx.x * blockDim.x + threadIdx.x;
    if (e < E) {
        int s = src[e], d = dst[e];
        int pos = atomicAdd(&cursor[d], 1);
        srcP[pos] = s;
        nrmP[pos] = dis[s] * ew[e] * dis[d];
    }
}

// Tiled GEMM: Hout = act(X) @ W  (BM64 x BN64 x BK32, 4x4 reg tile).
template<int K, int NOUT, bool RELU_IN>
__global__ __launch_bounds__(256) void k_gemm(
    const float* __restrict__ X, const float* __restrict__ W,
    float* __restrict__ Hout, int nrows)
{
    constexpr int BM = 64, BN = 64, BK = 32;
    __shared__ float As[BK][BM + 4];   // As[k][m]
    __shared__ float Bs[BK][BN + 4];

    const int tid = (int)threadIdx.x;
    const int tx  = tid & 15;          // cols tx*4..+3
    const int ty  = tid >> 4;          // rows ty*4..+3
    const int r0  = (int)blockIdx.x * BM;

    float acc[4][4] = {};

    for (int k0 = 0; k0 < K; k0 += BK) {
#pragma unroll
        for (int i = 0; i < (BM * BK) / 256; ++i) {
            int e  = tid + i * 256;
            int r  = e >> 5;
            int kk = e & 31;
            int row = r0 + r;
            float v = (row < nrows) ? X[(size_t)row * K + (k0 + kk)] : 0.f;
            if (RELU_IN) v = fmaxf(v, 0.f);
            As[kk][r] = v;
        }
#pragma unroll
        for (int i = 0; i < (BK * BN) / 256; ++i) {
            int e  = tid + i * 256;
            int kk = e >> 6;
            int c  = e & 63;
            Bs[kk][c] = (c < NOUT) ? W[(size_t)(k0 + kk) * NOUT + c] : 0.f;
        }
        __syncthreads();
#pragma unroll
        for (int kk = 0; kk < BK; ++kk) {
            float4 a = *(const float4*)&As[kk][ty * 4];
            float4 b = *(const float4*)&Bs[kk][tx * 4];
            acc[0][0] += a.x * b.x; acc[0][1] += a.x * b.y; acc[0][2] += a.x * b.z; acc[0][3] += a.x * b.w;
            acc[1][0] += a.y * b.x; acc[1][1] += a.y * b.y; acc[1][2] += a.y * b.z; acc[1][3] += a.y * b.w;
            acc[2][0] += a.z * b.x; acc[2][1] += a.z * b.y; acc[2][2] += a.z * b.z; acc[2][3] += a.z * b.w;
            acc[3][0] += a.w * b.x; acc[3][1] += a.w * b.y; acc[3][2] += a.w * b.z; acc[3][3] += a.w * b.w;
        }
        __syncthreads();
    }

    if (tx * 4 + 3 < NOUT) {
#pragma unroll
        for (int i = 0; i < 4; ++i) {
            int row = r0 + ty * 4 + i;
            if (row < nrows)
                *(float4*)&Hout[(size_t)row * NOUT + tx * 4] =
                    make_float4(acc[i][0], acc[i][1], acc[i][2], acc[i][3]);
        }
    }
}

// Gather aggregation: one wave per node, lane = feature. No atomics.
// out[row] = h[row]*dis[row]^2 + bias + sum_j h[srcP[j]] * nrmP[j]
template<int F>
__global__ __launch_bounds__(256) void k_node_agg(
    const float* __restrict__ h, const float* __restrict__ dis,
    const float* __restrict__ bias, const int* __restrict__ rowptr,
    const int* __restrict__ srcP, const float* __restrict__ nrmP,
    float* __restrict__ out, int n)
{
    const int lane = threadIdx.x & 63;
    int row = (int)((blockIdx.x * blockDim.x + threadIdx.x) >> 6);
    if (row >= n) return;
    row = __builtin_amdgcn_readfirstlane(row);   // wave-uniform -> SGPR addrs

    const int a = rowptr[row], b = rowptr[row + 1];
    float d  = dis[row];
    float dd = d * d;
    float sum = 0.f;
    if (lane < F) sum = h[(size_t)row * F + lane] * dd + bias[lane];

    int j = a;
    for (; j + 4 <= b; j += 4) {
        int   s0 = srcP[j],     s1 = srcP[j + 1], s2 = srcP[j + 2], s3 = srcP[j + 3];
        float w0 = nrmP[j],     w1 = nrmP[j + 1], w2 = nrmP[j + 2], w3 = nrmP[j + 3];
        if (lane < F) {
            sum += h[(size_t)s0 * F + lane] * w0;
            sum += h[(size_t)s1 * F + lane] * w1;
            sum += h[(size_t)s2 * F + lane] * w2;
            sum += h[(size_t)s3 * F + lane] * w3;
        }
    }
    for (; j < b; ++j) {
        int s = srcP[j]; float w = nrmP[j];
        if (lane < F) sum += h[(size_t)s * F + lane] * w;
    }
    if (lane < F) out[(size_t)row * F + lane] = sum;
}

// In-place log_softmax over C columns; one wave per row.
template<int C>
__global__ void k_logsoftmax(float* __restrict__ io, int n) {
    const int lane = threadIdx.x & 63;
    int row = (int)((blockIdx.x * blockDim.x + threadIdx.x) >> 6);
    if (row >= n) return;
    float v = (lane < C) ? io[(size_t)row * C + lane] : -INFINITY;
    float m = v;
#pragma unroll
    for (int off = 32; off; off >>= 1) m = fmaxf(m, __shfl_xor(m, off));
    float e = (lane < C) ? expf(v - m) : 0.f;
    float s = e;
#pragma unroll
    for (int off = 32; off; off >>= 1) s += __shfl_xor(s, off);
    float ls = logf(s);
    if (lane < C) io[(size_t)row * C + lane] = v - m - ls;
}

extern "C" void kernel_launch(void* const* d_in, const int* in_sizes, int n_in,
                              void* d_out, int out_size, void* d_ws, size_t ws_size,
                              hipStream_t stream) {
    const float* x  = (const float*)d_in[0];
    const int*   ei = (const int*)  d_in[1];
    const float* ew = (const float*)d_in[2];
    const float* W0 = (const float*)d_in[3];
    const float* b0 = (const float*)d_in[4];
    const float* W1 = (const float*)d_in[5];
    const float* b1 = (const float*)d_in[6];
    const float* W2 = (const float*)d_in[7];
    const float* b2 = (const float*)d_in[8];

    const int E   = in_sizes[2];            // 1600000
    const int H   = in_sizes[4];            // 64
    const int Fin = in_sizes[3] / H;        // 256
    const int N   = in_sizes[0] / Fin;      // 100000
    (void)n_in; (void)out_size; (void)ws_size;

    const int* srcv = ei;                   // edge_index[0]
    const int* dstv = ei + E;               // edge_index[1]

    // ---- workspace layout (all 256B-aligned chunks) ----
    float* ws = (float*)d_ws;
    size_t o = 0;
    auto alloc = [&](size_t cnt) { size_t p = o; o += (cnt + 63) & ~(size_t)63; return p; };
    float* dis   = ws + alloc(N);
    float* bufA  = ws + alloc((size_t)N * 64);   // h
    float* bufB  = ws + alloc((size_t)N * 64);   // agg
    float* nrmP  = ws + alloc(E);
    int*   rowptr= (int*)(ws + alloc(N + 1));
    int*   cursor= (int*)(ws + alloc(N));
    int*   cnt   = (int*)(ws + alloc(N));
    int*   srcP  = (int*)(ws + alloc(E));
    int*   bsum  = (int*)(ws + alloc(512));
    int*   boff  = (int*)(ws + alloc(512));
    float* outf  = (float*)d_out;                // N*40

    const int TB = 256;
    const int nb1 = (N + 255) / 256;             // scan blocks (391 <= 512)

    // ---- CSR build + norm precompute (shared across layers) ----
    k_init   <<<(N + TB - 1) / TB, TB, 0, stream>>>(dis, cnt, N);
    k_deg_cnt<<<(E + TB - 1) / TB, TB, 0, stream>>>(dstv, ew, dis, cnt, E);
    k_rsqrt  <<<(N + TB - 1) / TB, TB, 0, stream>>>(dis, N);
    k_scan1  <<<nb1, 256, 0, stream>>>(cnt, rowptr, bsum, N);
    k_scan2  <<<1, 512, 0, stream>>>(bsum, boff, nb1);
    k_scan3  <<<(N + TB - 1) / TB, TB, 0, stream>>>(rowptr, boff, cursor, N, E);
    k_scatter<<<(E + TB - 1) / TB, TB, 0, stream>>>(srcv, dstv, ew, dis, cursor,
                                                    srcP, nrmP, E);

    const int gemmGrid = (N + 63) / 64;
    const int aggGrid  = (N * 64 + TB - 1) / TB;     // one wave per node

    // ---- layer 0: x(256) -> 64 ----
    k_gemm<256, 64, false><<<gemmGrid, TB, 0, stream>>>(x, W0, bufA, N);
    k_node_agg<64><<<aggGrid, TB, 0, stream>>>(bufA, dis, b0, rowptr, srcP, nrmP, bufB, N);

    // ---- layer 1: 64 -> 64 (relu on load) ----
    k_gemm<64, 64, true><<<gemmGrid, TB, 0, stream>>>(bufB, W1, bufA, N);
    k_node_agg<64><<<aggGrid, TB, 0, stream>>>(bufA, dis, b1, rowptr, srcP, nrmP, bufB, N);

    // ---- layer 2: 64 -> 40, aggregate straight into d_out ----
    k_gemm<64, 40, true><<<gemmGrid, TB, 0, stream>>>(bufB, W2, bufA, N);
    k_node_agg<40><<<aggGrid, TB, 0, stream>>>(bufA, dis, b2, rowptr, srcP, nrmP, outf, N);

    // ---- log_softmax in-place on d_out ----
    k_logsoftmax<40><<<(N * 64 + TB - 1) / TB, TB, 0, stream>>>(outf, N);
}

// Round 8
// 439.141 us; speedup vs baseline: 4.0534x; 1.3348x over previous
//
#include <hip/hip_runtime.h>
#include <math.h>

// ---------------------------------------------------------------------------
// GCN 3-layer forward for MI355X.
// R5: tiled GEMM (733->~40us). R6->R7: CSR gather agg, no per-layer atomics
//   (1161->586us). R7 profile: build kernels dominate (scatter 145, deg_cnt
//   142us); WRITE_SIZE shows every scattered 4B atomic/store costs a 32B HBM
//   sector (write-through atomics).
// R8: counting-sort build with ONE atomic per edge total:
//   k_cnt: pos[e]=atomicAdd(cnt[dst]) (slot = return value)
//   scan -> rowptr ; k_place: pairP[rowptr[d]+pos[e]] = pack(src,ew) (8B, no
//   atomic) ; k_deg_dis: dis=rsqrt(1+sum ew) from CSR (no deg atomics) ;
//   k_norm_csr: pair payload ew -> dis[s]*ew*dis[d] in place.
//   Scattered sectors/edge: 5 -> 2.
// ---------------------------------------------------------------------------

__global__ void k_cnt(const int* __restrict__ dst, int* __restrict__ cnt,
                      int* __restrict__ pos, int E) {
    int e = blockIdx.x * blockDim.x + threadIdx.x;
    if (e < E) pos[e] = atomicAdd(&cnt[dst[e]], 1);
}

// ---- exclusive scan over cnt[N] -> rowptr, 3 kernels ----
__global__ void k_scan1(const int* __restrict__ cnt, int* __restrict__ excl,
                        int* __restrict__ bsum, int n) {
    __shared__ int sm[256];
    int tid = threadIdx.x;
    int i = blockIdx.x * 256 + tid;
    int v = (i < n) ? cnt[i] : 0;
    sm[tid] = v;
    __syncthreads();
    for (int off = 1; off < 256; off <<= 1) {
        int t = (tid >= off) ? sm[tid - off] : 0;
        __syncthreads();
        sm[tid] += t;
        __syncthreads();
    }
    if (i < n) excl[i] = sm[tid] - v;
    if (tid == 255) bsum[blockIdx.x] = sm[255];
}

__global__ void k_scan2(const int* __restrict__ bsum, int* __restrict__ boff, int nb) {
    __shared__ int sm[512];
    int tid = threadIdx.x;
    int v = (tid < nb) ? bsum[tid] : 0;
    sm[tid] = v;
    __syncthreads();
    for (int off = 1; off < 512; off <<= 1) {
        int t = (tid >= off) ? sm[tid - off] : 0;
        __syncthreads();
        sm[tid] += t;
        __syncthreads();
    }
    boff[tid] = sm[tid] - v;   // exclusive
}

__global__ void k_scan3(int* __restrict__ rowptr, const int* __restrict__ boff,
                        int n, int E) {
    int i = blockIdx.x * blockDim.x + threadIdx.x;
    if (i < n) rowptr[i] += boff[i >> 8];
    if (i == 0) rowptr[n] = E;
}

// Place edges into dst-grouped slots (NO atomic): 8B packed {src, ew}.
__global__ void k_place(const int* __restrict__ src, const int* __restrict__ dst,
                        const float* __restrict__ ew, const int* __restrict__ rowptr,
                        const int* __restrict__ pos, unsigned long long* __restrict__ pairP,
                        int E) {
    int e = blockIdx.x * blockDim.x + threadIdx.x;
    if (e < E) {
        int d = dst[e];
        int p = rowptr[d] + pos[e];
        unsigned long long pk = (unsigned long long)__float_as_uint(ew[e]) << 32
                              | (unsigned int)src[e];
        pairP[p] = pk;
    }
}

// Per-node: dis = rsqrt(1 + sum ew) from CSR pairs (payload = ew here).
__global__ void k_deg_dis(const unsigned long long* __restrict__ pairP,
                          const int* __restrict__ rowptr, float* __restrict__ dis, int n) {
    int i = blockIdx.x * blockDim.x + threadIdx.x;
    if (i >= n) return;
    int a = rowptr[i], b = rowptr[i + 1];
    float s = 1.0f;   // self-loop weight
    for (int p = a; p < b; ++p)
        s += __uint_as_float((unsigned int)(pairP[p] >> 32));
    dis[i] = (s > 0.f) ? rsqrtf(s) : 0.f;
}

// Per-node: rewrite pair payload ew -> nrm = dis[s]*ew*dis[d] (in place).
__global__ void k_norm_csr(unsigned long long* __restrict__ pairP,
                           const int* __restrict__ rowptr,
                           const float* __restrict__ dis, int n) {
    int i = blockIdx.x * blockDim.x + threadIdx.x;
    if (i >= n) return;
    int a = rowptr[i], b = rowptr[i + 1];
    float dd = dis[i];
    for (int p = a; p < b; ++p) {
        unsigned long long pk = pairP[p];
        int s = (int)(unsigned int)pk;
        float w = __uint_as_float((unsigned int)(pk >> 32));
        float nrm = dis[s] * w * dd;
        pairP[p] = ((unsigned long long)__float_as_uint(nrm) << 32) | (unsigned int)s;
    }
}

// Tiled GEMM: Hout = act(X) @ W  (BM64 x BN64 x BK32, 4x4 reg tile).
template<int K, int NOUT, bool RELU_IN>
__global__ __launch_bounds__(256) void k_gemm(
    const float* __restrict__ X, const float* __restrict__ W,
    float* __restrict__ Hout, int nrows)
{
    constexpr int BM = 64, BN = 64, BK = 32;
    __shared__ float As[BK][BM + 4];   // As[k][m]
    __shared__ float Bs[BK][BN + 4];

    const int tid = (int)threadIdx.x;
    const int tx  = tid & 15;          // cols tx*4..+3
    const int ty  = tid >> 4;          // rows ty*4..+3
    const int r0  = (int)blockIdx.x * BM;

    float acc[4][4] = {};

    for (int k0 = 0; k0 < K; k0 += BK) {
#pragma unroll
        for (int i = 0; i < (BM * BK) / 256; ++i) {
            int e  = tid + i * 256;
            int r  = e >> 5;
            int kk = e & 31;
            int row = r0 + r;
            float v = (row < nrows) ? X[(size_t)row * K + (k0 + kk)] : 0.f;
            if (RELU_IN) v = fmaxf(v, 0.f);
            As[kk][r] = v;
        }
#pragma unroll
        for (int i = 0; i < (BK * BN) / 256; ++i) {
            int e  = tid + i * 256;
            int kk = e >> 6;
            int c  = e & 63;
            Bs[kk][c] = (c < NOUT) ? W[(size_t)(k0 + kk) * NOUT + c] : 0.f;
        }
        __syncthreads();
#pragma unroll
        for (int kk = 0; kk < BK; ++kk) {
            float4 a = *(const float4*)&As[kk][ty * 4];
            float4 b = *(const float4*)&Bs[kk][tx * 4];
            acc[0][0] += a.x * b.x; acc[0][1] += a.x * b.y; acc[0][2] += a.x * b.z; acc[0][3] += a.x * b.w;
            acc[1][0] += a.y * b.x; acc[1][1] += a.y * b.y; acc[1][2] += a.y * b.z; acc[1][3] += a.y * b.w;
            acc[2][0] += a.z * b.x; acc[2][1] += a.z * b.y; acc[2][2] += a.z * b.z; acc[2][3] += a.z * b.w;
            acc[3][0] += a.w * b.x; acc[3][1] += a.w * b.y; acc[3][2] += a.w * b.z; acc[3][3] += a.w * b.w;
        }
        __syncthreads();
    }

    if (tx * 4 + 3 < NOUT) {
#pragma unroll
        for (int i = 0; i < 4; ++i) {
            int row = r0 + ty * 4 + i;
            if (row < nrows)
                *(float4*)&Hout[(size_t)row * NOUT + tx * 4] =
                    make_float4(acc[i][0], acc[i][1], acc[i][2], acc[i][3]);
        }
    }
}

// Gather aggregation: one wave per node, lane = feature. No atomics.
// out[row] = h[row]*dis[row]^2 + bias + sum_j h[src_j] * nrm_j  (packed pairs)
template<int F>
__global__ __launch_bounds__(256) void k_node_agg(
    const float* __restrict__ h, const float* __restrict__ dis,
    const float* __restrict__ bias, const int* __restrict__ rowptr,
    const unsigned long long* __restrict__ pairP,
    float* __restrict__ out, int n)
{
    const int lane = threadIdx.x & 63;
    int row = (int)((blockIdx.x * blockDim.x + threadIdx.x) >> 6);
    if (row >= n) return;
    row = __builtin_amdgcn_readfirstlane(row);   // wave-uniform -> SGPR addrs

    const int a = rowptr[row], b = rowptr[row + 1];
    float d  = dis[row];
    float dd = d * d;
    float sum = 0.f;
    if (lane < F) sum = h[(size_t)row * F + lane] * dd + bias[lane];

    int j = a;
    for (; j + 4 <= b; j += 4) {
        unsigned long long p0 = pairP[j],     p1 = pairP[j + 1];
        unsigned long long p2 = pairP[j + 2], p3 = pairP[j + 3];
        int   s0 = (int)(unsigned int)p0, s1 = (int)(unsigned int)p1;
        int   s2 = (int)(unsigned int)p2, s3 = (int)(unsigned int)p3;
        float w0 = __uint_as_float((unsigned int)(p0 >> 32));
        float w1 = __uint_as_float((unsigned int)(p1 >> 32));
        float w2 = __uint_as_float((unsigned int)(p2 >> 32));
        float w3 = __uint_as_float((unsigned int)(p3 >> 32));
        if (lane < F) {
            sum += h[(size_t)s0 * F + lane] * w0;
            sum += h[(size_t)s1 * F + lane] * w1;
            sum += h[(size_t)s2 * F + lane] * w2;
            sum += h[(size_t)s3 * F + lane] * w3;
        }
    }
    for (; j < b; ++j) {
        unsigned long long p = pairP[j];
        int s = (int)(unsigned int)p;
        float w = __uint_as_float((unsigned int)(p >> 32));
        if (lane < F) sum += h[(size_t)s * F + lane] * w;
    }
    if (lane < F) out[(size_t)row * F + lane] = sum;
}

// In-place log_softmax over C columns; one wave per row.
template<int C>
__global__ void k_logsoftmax(float* __restrict__ io, int n) {
    const int lane = threadIdx.x & 63;
    int row = (int)((blockIdx.x * blockDim.x + threadIdx.x) >> 6);
    if (row >= n) return;
    float v = (lane < C) ? io[(size_t)row * C + lane] : -INFINITY;
    float m = v;
#pragma unroll
    for (int off = 32; off; off >>= 1) m = fmaxf(m, __shfl_xor(m, off));
    float e = (lane < C) ? expf(v - m) : 0.f;
    float s = e;
#pragma unroll
    for (int off = 32; off; off >>= 1) s += __shfl_xor(s, off);
    float ls = logf(s);
    if (lane < C) io[(size_t)row * C + lane] = v - m - ls;
}

extern "C" void kernel_launch(void* const* d_in, const int* in_sizes, int n_in,
                              void* d_out, int out_size, void* d_ws, size_t ws_size,
                              hipStream_t stream) {
    const float* x  = (const float*)d_in[0];
    const int*   ei = (const int*)  d_in[1];
    const float* ew = (const float*)d_in[2];
    const float* W0 = (const float*)d_in[3];
    const float* b0 = (const float*)d_in[4];
    const float* W1 = (const float*)d_in[5];
    const float* b1 = (const float*)d_in[6];
    const float* W2 = (const float*)d_in[7];
    const float* b2 = (const float*)d_in[8];

    const int E   = in_sizes[2];            // 1600000
    const int H   = in_sizes[4];            // 64
    const int Fin = in_sizes[3] / H;        // 256
    const int N   = in_sizes[0] / Fin;      // 100000
    (void)n_in; (void)out_size; (void)ws_size;

    const int* srcv = ei;                   // edge_index[0]
    const int* dstv = ei + E;               // edge_index[1]

    // ---- workspace layout (64-float = 256B aligned chunks; 8B-safe) ----
    float* ws = (float*)d_ws;
    size_t o = 0;
    auto alloc = [&](size_t cnt) { size_t p = o; o += (cnt + 63) & ~(size_t)63; return p; };
    float* dis   = ws + alloc(N);
    float* bufA  = ws + alloc((size_t)N * 64);       // h
    float* bufB  = ws + alloc((size_t)N * 64);       // agg
    unsigned long long* pairP = (unsigned long long*)(ws + alloc((size_t)E * 2));
    int*   rowptr= (int*)(ws + alloc(N + 1));
    int*   cnt   = (int*)(ws + alloc(N));
    int*   pos   = (int*)(ws + alloc(E));
    int*   bsum  = (int*)(ws + alloc(512));
    int*   boff  = (int*)(ws + alloc(512));
    float* outf  = (float*)d_out;                    // N*40

    const int TB = 256;
    const int nb1 = (N + 255) / 256;                 // scan blocks (391 <= 512)

    // ---- CSR build (counting sort, 1 atomic/edge total) ----
    hipMemsetAsync(cnt, 0, (size_t)N * sizeof(int), stream);
    k_cnt  <<<(E + TB - 1) / TB, TB, 0, stream>>>(dstv, cnt, pos, E);
    k_scan1<<<nb1, 256, 0, stream>>>(cnt, rowptr, bsum, N);
    k_scan2<<<1, 512, 0, stream>>>(bsum, boff, nb1);
    k_scan3<<<(N + TB - 1) / TB, TB, 0, stream>>>(rowptr, boff, N, E);
    k_place<<<(E + TB - 1) / TB, TB, 0, stream>>>(srcv, dstv, ew, rowptr, pos, pairP, E);
    k_deg_dis <<<(N + TB - 1) / TB, TB, 0, stream>>>(pairP, rowptr, dis, N);
    k_norm_csr<<<(N + TB - 1) / TB, TB, 0, stream>>>(pairP, rowptr, dis, N);

    const int gemmGrid = (N + 63) / 64;
    const int aggGrid  = (N * 64 + TB - 1) / TB;     // one wave per node

    // ---- layer 0: x(256) -> 64 ----
    k_gemm<256, 64, false><<<gemmGrid, TB, 0, stream>>>(x, W0, bufA, N);
    k_node_agg<64><<<aggGrid, TB, 0, stream>>>(bufA, dis, b0, rowptr, pairP, bufB, N);

    // ---- layer 1: 64 -> 64 (relu on load) ----
    k_gemm<64, 64, true><<<gemmGrid, TB, 0, stream>>>(bufB, W1, bufA, N);
    k_node_agg<64><<<aggGrid, TB, 0, stream>>>(bufA, dis, b1, rowptr, pairP, bufB, N);

    // ---- layer 2: 64 -> 40, aggregate straight into d_out ----
    k_gemm<64, 40, true><<<gemmGrid, TB, 0, stream>>>(bufB, W2, bufA, N);
    k_node_agg<40><<<aggGrid, TB, 0, stream>>>(bufA, dis, b2, rowptr, pairP, outf, N);

    // ---- log_softmax in-place on d_out ----
    k_logsoftmax<40><<<(N * 64 + TB - 1) / TB, TB, 0, stream>>>(outf, N);
}